// Round 9
// baseline (296.180 us; speedup 1.0000x reference)
//
#include <hip/hip_runtime.h>

// JointNet: out[n,t,u,v] = tanh(enc_proj[t,n,:] + pred_proj[u,n,:] + b1) . W2^T + b2
// T=200 U=50 N=8  ENC=PRED=512  H=640  V=1000
// m = ((n*200+t)*50+u) -> flat row-major [80000][1000] GEMM.
// Round-9: k_hidden materializes tanh once (bf16). k_joint = pure GEMM, 256x256 tile,
// BK=64, double-buffered 128KB LDS, counted vmcnt(8) pipeline (stage(t+1) in flight
// across MFMA(t)), raw barriers. Both operands via global_load_lds w/ swizzled source.

typedef __attribute__((ext_vector_type(4))) float f32x4;
typedef __attribute__((ext_vector_type(8))) short s16x8;

#define HDIM 640
#define VOCAB 1000

__device__ __forceinline__ float tanh_fast(float x) {
  float e = __expf(2.0f * x);
  return 1.0f - 2.0f * __builtin_amdgcn_rcpf(e + 1.0f);
}

__device__ __forceinline__ unsigned short f2bf(float f) {
  unsigned int u = __float_as_uint(f);
  return (unsigned short)((u + 0x7FFFu + ((u >> 16) & 1u)) >> 16);  // RNE
}

__device__ __forceinline__ void gload_lds16(const void* g, void* l) {
  __builtin_amdgcn_global_load_lds((const __attribute__((address_space(1))) void*)g,
                                   (__attribute__((address_space(3))) void*)l, 16, 0, 0);
}

// ---- K0: W2 f32 [1000][640] -> bf16 [1024][640], rows 1000..1023 zero ----
__global__ void k_prep(const float* __restrict__ W2, unsigned short* __restrict__ W2b) {
  int i = blockIdx.x * 256 + threadIdx.x;  // 81920 = 1024*640/8
  int v = i / 80;
  int kc = (i - v * 80) * 8;
  s16x8 o = {0, 0, 0, 0, 0, 0, 0, 0};
  if (v < VOCAB) {
    const float* src = W2 + v * HDIM + kc;
    f32x4 a = *(const f32x4*)src;
    f32x4 b = *(const f32x4*)(src + 4);
#pragma unroll
    for (int j = 0; j < 4; ++j) {
      o[j] = (short)f2bf(a[j]);
      o[j + 4] = (short)f2bf(b[j]);
    }
  }
  *(s16x8*)(W2b + (size_t)v * HDIM + kc) = o;
}

// ---- K1: projections, f32 tiled GEMM ----
__global__ __launch_bounds__(256) void k_proj(const float* __restrict__ enc,
                                              const float* __restrict__ pred,
                                              const float* __restrict__ W1,
                                              const float* __restrict__ b1,
                                              float* __restrict__ EPPB) {
  __shared__ float As[16][68];
  __shared__ float Bs[16][68];
  const int tid = threadIdx.x;
  const int tx = tid & 15, ty = tid >> 4;
  const int h0 = blockIdx.x * 64;
  const int m0 = blockIdx.y * 64;
  const bool isPred = (m0 >= 1600);
  const float* A = isPred ? pred : enc;
  const int arow0 = isPred ? (m0 - 1600) : m0;
  const int armax = isPred ? 399 : 1599;
  const int koff = isPred ? 512 : 0;
  float acc[4][4] = {};
  for (int k0 = 0; k0 < 512; k0 += 16) {
#pragma unroll
    for (int q = 0; q < 4; ++q) {
      int r = ty + q * 16;
      int ar = arow0 + r;
      if (ar > armax) ar = armax;
      As[tx][r] = A[ar * 512 + k0 + tx];
      Bs[tx][r] = W1[(h0 + r) * 1024 + koff + k0 + tx];
    }
    __syncthreads();
#pragma unroll
    for (int kk = 0; kk < 16; ++kk) {
      f32x4 a = *(const f32x4*)&As[kk][ty * 4];
      f32x4 b = *(const f32x4*)&Bs[kk][tx * 4];
#pragma unroll
      for (int i = 0; i < 4; ++i)
#pragma unroll
        for (int j = 0; j < 4; ++j) acc[i][j] += a[i] * b[j];
    }
    __syncthreads();
  }
#pragma unroll
  for (int i = 0; i < 4; ++i) {
    int m = m0 + ty * 4 + i;
    if (m < 2000) {
#pragma unroll
      for (int j = 0; j < 4; ++j) {
        int h = h0 + tx * 4 + j;
        float val = acc[i][j];
        if (m >= 1600) val += b1[h];
        EPPB[m * HDIM + h] = val;
      }
    }
  }
}

// ---- K1b: hidden = tanh(ep + pb) -> bf16 Hb[80128][640], linear, once ----
__global__ __launch_bounds__(256) void k_hidden(const float* __restrict__ EPPB,
                                                unsigned short* __restrict__ Hb) {
  const int tid = threadIdx.x;
  const int wave = tid >> 6, lane = tid & 63;
  const int r = lane >> 3, c = lane & 7;  // 8 rows x 8 k-chunks per wave
  const int m = blockIdx.x * 32 + wave * 8 + r;
  const int ms = (m < 80000) ? m : 79999;  // pad rows clone row 79999
  const int n = ms / 10000;
  const int rr = ms - n * 10000;
  const int t = rr / 50;
  const int u = rr - t * 50;
  const float* ep = EPPB + (t * 8 + n) * HDIM + c * 8;
  const float* pb = EPPB + (1600 + u * 8 + n) * HDIM + c * 8;
  unsigned short* hrow = Hb + (size_t)m * HDIM + c * 8;
#pragma unroll
  for (int it = 0; it < 10; ++it) {
    const int k = it * 64;
    f32x4 e0 = *(const f32x4*)(ep + k);
    f32x4 e1 = *(const f32x4*)(ep + k + 4);
    f32x4 p0 = *(const f32x4*)(pb + k);
    f32x4 p1 = *(const f32x4*)(pb + k + 4);
    s16x8 h;
#pragma unroll
    for (int i = 0; i < 4; ++i) {
      h[i] = (short)f2bf(tanh_fast(e0[i] + p0[i]));
      h[i + 4] = (short)f2bf(tanh_fast(e1[i] + p1[i]));
    }
    *(s16x8*)(hrow + k) = h;
  }
}

// ---- K2: pure GEMM 256m x 256v, BK=64, dbuf LDS, counted-vmcnt pipeline ----
#define STAGE(ks, base)                                                                  \
  _Pragma("unroll") for (int s = 0; s < 4; ++s) {                                        \
    gload_lds16(hbytes + agoff[s] + (ks) * 128, lds + (base) + s * 8192 + tid * 16);     \
    gload_lds16(w2bytes + bgoff[s] + (ks) * 128,                                         \
                lds + (base) + 32768 + s * 8192 + tid * 16);                             \
  }

__global__ __launch_bounds__(512, 2) void k_joint(const unsigned short* __restrict__ Hb,
                                                  const unsigned short* __restrict__ W2b,
                                                  const float* __restrict__ b2,
                                                  float* __restrict__ out) {
  extern __shared__ char lds[];  // 131072: buf0 {A 32K | B 32K} buf1 {A | B}

  // bijective XCD-chunked swizzle over 1252 WGs (1252 = 8*156 + 4); vtile-minor
  const int bid = blockIdx.x;
  const int xcd = bid & 7, seq = bid >> 3;
  const int swz = (xcd < 4 ? xcd * 157 : 628 + (xcd - 4) * 156) + seq;
  const int mtile = swz >> 2;
  const int vtile = swz & 3;
  const int m0 = mtile * 256;
  const int v0 = vtile * 256;

  const int tid = threadIdx.x;
  const char* const hbytes = (const char*)Hb;
  const char* const w2bytes = (const char*)W2b;

  // staging: 4 A-chunks + 4 B-chunks per thread (2048 = 256 rows x 8 kchunks each)
  int agoff[4], bgoff[4];
#pragma unroll
  for (int s = 0; s < 4; ++s) {
    int c = s * 512 + tid;
    int row = c >> 3, kc = c & 7;
    int so = (kc * 16) ^ ((row & 7) << 4);  // pre-swizzled source offset
    agoff[s] = (m0 + row) * 1280 + so;
    bgoff[s] = (v0 + row) * 1280 + so;
  }

  const int wid = tid >> 6;
  const int lane = tid & 63;
  const int mrow = (wid >> 2) * 128;  // 2 m-waves x 4 v-waves
  const int vrow = (wid & 3) * 64;
  const int lr = lane & 15;
  const int kq = lane >> 4;
  const int sw = (lr & 7) << 4;

  f32x4 acc[8][4];
  const f32x4 zero = {0.0f, 0.0f, 0.0f, 0.0f};
#pragma unroll
  for (int mi = 0; mi < 8; ++mi)
#pragma unroll
    for (int ni = 0; ni < 4; ++ni) acc[mi][ni] = zero;

  STAGE(0, 0);  // prologue: K-step 0 -> buf0

#pragma unroll 1
  for (int t = 0; t < 10; ++t) {
    const int cb = (t & 1) * 65536;
    if (t < 9) {
      const int nb = ((t + 1) & 1) * 65536;
      STAGE(t + 1, nb);  // stays in flight across this step's MFMAs
      asm volatile("s_waitcnt vmcnt(8)" ::: "memory");  // stage(t) landed
    } else {
      asm volatile("s_waitcnt vmcnt(0)" ::: "memory");
    }
    __builtin_amdgcn_sched_barrier(0);
    asm volatile("s_barrier" ::: "memory");  // all waves' stage(t) visible

    const char* Ac = lds + cb;
    const char* Bc = lds + cb + 32768;
#pragma unroll
    for (int kk = 0; kk < 2; ++kk) {
      const int kt = (kk * 64 + kq * 16) ^ sw;
      s16x8 afr[8], bfr[4];
#pragma unroll
      for (int mi = 0; mi < 8; ++mi)
        afr[mi] = *(const s16x8*)(Ac + (mrow + mi * 16 + lr) * 128 + kt);
#pragma unroll
      for (int ni = 0; ni < 4; ++ni)
        bfr[ni] = *(const s16x8*)(Bc + (vrow + ni * 16 + lr) * 128 + kt);
      __builtin_amdgcn_s_setprio(1);
#pragma unroll
      for (int mi = 0; mi < 8; ++mi)
#pragma unroll
        for (int ni = 0; ni < 4; ++ni)
          // swapped operands: D row = v (4 consecutive per lane), col = m
          acc[mi][ni] = __builtin_amdgcn_mfma_f32_16x16x32_bf16(bfr[ni], afr[mi], acc[mi][ni], 0, 0, 0);
      __builtin_amdgcn_s_setprio(0);
    }
    asm volatile("s_barrier" ::: "memory");  // reads done before buf[nxt] overwrite
  }

  // epilogue: lane holds 4 consecutive v per acc reg -> float4 stores
#pragma unroll
  for (int ni = 0; ni < 4; ++ni) {
    int vq = v0 + vrow + ni * 16 + kq * 4;
    if (vq < VOCAB) {
      f32x4 bv = *(const f32x4*)(b2 + vq);
#pragma unroll
      for (int mi = 0; mi < 8; ++mi) {
        int m = m0 + mrow + mi * 16 + lr;
        if (m < 80000) {
          f32x4 r = acc[mi][ni] + bv;
          *(f32x4*)(out + (size_t)m * VOCAB + vq) = r;
        }
      }
    }
  }
}

// ---- Fallback: round-7 fused kernel (proven 210 us) if workspace too small ----
__global__ __launch_bounds__(256, 2) void k_joint_fused(const float* __restrict__ EPPB,
                                                        const unsigned short* __restrict__ W2b,
                                                        const float* __restrict__ b2,
                                                        float* __restrict__ out) {
  __shared__ char Asm[16384];
  __shared__ char Bsm[32768];

  const int bid = blockIdx.x;
  const int xcd = bid & 7, seq = bid >> 3;
  const int swz = (xcd < 4 ? xcd * 313 : 1252 + (xcd - 4) * 312) + seq;
  const int mtile = swz >> 2;
  const int vtile = swz & 3;
  const int m0 = mtile * 128;
  const int v0 = vtile * 256;

  const int tid = threadIdx.x;

  int epoff[4], pboff[4], aoff[4];
#pragma unroll
  for (int s = 0; s < 4; ++s) {
    int c = s * 256 + tid;
    int row = c >> 3, kc = c & 7;
    int m = m0 + row;
    int n = m / 10000;
    int rr = m - n * 10000;
    int t = rr / 50;
    int u = rr - t * 50;
    epoff[s] = (t * 8 + n) * HDIM + kc * 8;
    pboff[s] = (1600 + u * 8 + n) * HDIM + kc * 8;
    aoff[s] = row * 128 + ((kc * 16) ^ ((row & 7) << 4));
  }

  const char* const w2bytes = (const char*)W2b;
  int bgoff[8];
#pragma unroll
  for (int s = 0; s < 8; ++s) {
    int c = s * 256 + tid;
    int row = c >> 3, kc = c & 7;
    bgoff[s] = (v0 + row) * 1280 + ((kc * 16) ^ ((row & 7) << 4));
  }
  const int bldsbase = (tid >> 6) * 1024;

  const int wid = tid >> 6;
  const int lane = tid & 63;
  const int mrow = (wid >> 1) * 64;
  const int vrow = (wid & 1) * 128;
  const int lr = lane & 15;
  const int kq = lane >> 4;
  const int sw = (lr & 7) << 4;

  f32x4 acc[4][8];
  const f32x4 zero = {0.0f, 0.0f, 0.0f, 0.0f};
#pragma unroll
  for (int mi = 0; mi < 4; ++mi)
#pragma unroll
    for (int ni = 0; ni < 8; ++ni) acc[mi][ni] = zero;

#pragma unroll 1
  for (int ks = 0; ks < 10; ++ks) {
    s16x8 aq[4];
#pragma unroll
    for (int s = 0; s < 4; ++s) {
      const float* ep = EPPB + epoff[s] + ks * 64;
      const float* pb = EPPB + pboff[s] + ks * 64;
      f32x4 e0 = *(const f32x4*)ep;
      f32x4 e1 = *(const f32x4*)(ep + 4);
      f32x4 p0 = *(const f32x4*)pb;
      f32x4 p1 = *(const f32x4*)(pb + 4);
#pragma unroll
      for (int i = 0; i < 4; ++i) {
        aq[s][i] = (short)f2bf(tanh_fast(e0[i] + p0[i]));
        aq[s][i + 4] = (short)f2bf(tanh_fast(e1[i] + p1[i]));
      }
    }
    __syncthreads();
#pragma unroll
    for (int s = 0; s < 8; ++s)
      gload_lds16(w2bytes + bgoff[s] + ks * 128, Bsm + s * 4096 + bldsbase);
#pragma unroll
    for (int s = 0; s < 4; ++s) *(s16x8*)(Asm + aoff[s]) = aq[s];
    __syncthreads();

#pragma unroll
    for (int kk = 0; kk < 2; ++kk) {
      const int kt = (kk * 64 + kq * 16) ^ sw;
      s16x8 afr[4], bfr[8];
#pragma unroll
      for (int mi = 0; mi < 4; ++mi)
        afr[mi] = *(const s16x8*)(Asm + (mrow + mi * 16 + lr) * 128 + kt);
#pragma unroll
      for (int ni = 0; ni < 8; ++ni)
        bfr[ni] = *(const s16x8*)(Bsm + (vrow + ni * 16 + lr) * 128 + kt);
      __builtin_amdgcn_s_setprio(1);
#pragma unroll
      for (int mi = 0; mi < 4; ++mi)
#pragma unroll
        for (int ni = 0; ni < 8; ++ni)
          acc[mi][ni] = __builtin_amdgcn_mfma_f32_16x16x32_bf16(bfr[ni], afr[mi], acc[mi][ni], 0, 0, 0);
      __builtin_amdgcn_s_setprio(0);
    }
  }

#pragma unroll
  for (int ni = 0; ni < 8; ++ni) {
    int vq = v0 + vrow + ni * 16 + kq * 4;
    if (vq < VOCAB) {
      f32x4 bv = *(const f32x4*)(b2 + vq);
#pragma unroll
      for (int mi = 0; mi < 4; ++mi) {
        int m = m0 + mrow + mi * 16 + lr;
        f32x4 r = acc[mi][ni] + bv;
        *(f32x4*)(out + (size_t)m * VOCAB + vq) = r;
      }
    }
  }
}

extern "C" void kernel_launch(void* const* d_in, const int* in_sizes, int n_in,
                              void* d_out, int out_size, void* d_ws, size_t ws_size,
                              hipStream_t stream) {
  const float* enc = (const float*)d_in[0];
  const float* pred = (const float*)d_in[1];
  const float* W1 = (const float*)d_in[2];
  const float* b1 = (const float*)d_in[3];
  const float* W2 = (const float*)d_in[4];
  const float* b2 = (const float*)d_in[5];
  float* out = (float*)d_out;

  unsigned short* W2b = (unsigned short*)d_ws;                    // 1,310,720 B
  float* EPPB = (float*)((char*)d_ws + 1310720);                  // 5,120,000 B
  unsigned short* Hb = (unsigned short*)((char*)d_ws + 6430720);  // 80128*1280 B

  k_prep<<<320, 256, 0, stream>>>(W2, W2b);
  k_proj<<<dim3(10, 32), 256, 0, stream>>>(enc, pred, W1, b1, EPPB);

  if (ws_size >= (size_t)108994560) {
    hipFuncSetAttribute((const void*)k_joint, hipFuncAttributeMaxDynamicSharedMemorySize, 131072);
    k_hidden<<<2504, 256, 0, stream>>>(EPPB, Hb);
    k_joint<<<1252, 512, 131072, stream>>>(Hb, W2b, b2, out);
  } else {
    k_joint_fused<<<2500, 256, 0, stream>>>(EPPB, W2b, b2, out);
  }
}

// Round 12
// 283.333 us; speedup vs baseline: 1.0453x; 1.0453x over previous
//
#include <hip/hip_runtime.h>

// JointNet: out[n,t,u,v] = tanh(enc_proj[t,n,:] + pred_proj[u,n,:] + b1) . W2^T + b2
// T=200 U=50 N=8  ENC=PRED=512  H=640  V=1000
// m = ((n*200+t)*50+u) -> flat row-major [80000][1000] GEMM.
// Round-12: round-11 4-phase pipeline + prologue publication fix (vmcnt(0)+barrier
// after staging K-tile 0 — R11's NaN was t=0 c0 reading LDS before the prologue's
// global_load_lds retired/published).

typedef __attribute__((ext_vector_type(4))) float f32x4;
typedef __attribute__((ext_vector_type(8))) short s16x8;

#define HDIM 640
#define VOCAB 1000

__device__ __forceinline__ float tanh_fast(float x) {
  float e = __expf(2.0f * x);
  return 1.0f - 2.0f * __builtin_amdgcn_rcpf(e + 1.0f);
}

__device__ __forceinline__ unsigned short f2bf(float f) {
  unsigned int u = __float_as_uint(f);
  return (unsigned short)((u + 0x7FFFu + ((u >> 16) & 1u)) >> 16);  // RNE
}

__device__ __forceinline__ void gload_lds16(const void* g, void* l) {
  __builtin_amdgcn_global_load_lds((const __attribute__((address_space(1))) void*)g,
                                   (__attribute__((address_space(3))) void*)l, 16, 0, 0);
}

// ---- K0: W2 f32 [1000][640] -> bf16 [1024][640], rows 1000..1023 zero ----
__global__ void k_prep(const float* __restrict__ W2, unsigned short* __restrict__ W2b) {
  int i = blockIdx.x * 256 + threadIdx.x;  // 81920 = 1024*640/8
  int v = i / 80;
  int kc = (i - v * 80) * 8;
  s16x8 o = {0, 0, 0, 0, 0, 0, 0, 0};
  if (v < VOCAB) {
    const float* src = W2 + v * HDIM + kc;
    f32x4 a = *(const f32x4*)src;
    f32x4 b = *(const f32x4*)(src + 4);
#pragma unroll
    for (int j = 0; j < 4; ++j) {
      o[j] = (short)f2bf(a[j]);
      o[j + 4] = (short)f2bf(b[j]);
    }
  }
  *(s16x8*)(W2b + (size_t)v * HDIM + kc) = o;
}

// ---- K1: projections, f32 tiled GEMM ----
__global__ __launch_bounds__(256) void k_proj(const float* __restrict__ enc,
                                              const float* __restrict__ pred,
                                              const float* __restrict__ W1,
                                              const float* __restrict__ b1,
                                              float* __restrict__ EPPB) {
  __shared__ float As[16][68];
  __shared__ float Bs[16][68];
  const int tid = threadIdx.x;
  const int tx = tid & 15, ty = tid >> 4;
  const int h0 = blockIdx.x * 64;
  const int m0 = blockIdx.y * 64;
  const bool isPred = (m0 >= 1600);
  const float* A = isPred ? pred : enc;
  const int arow0 = isPred ? (m0 - 1600) : m0;
  const int armax = isPred ? 399 : 1599;
  const int koff = isPred ? 512 : 0;
  float acc[4][4] = {};
  for (int k0 = 0; k0 < 512; k0 += 16) {
#pragma unroll
    for (int q = 0; q < 4; ++q) {
      int r = ty + q * 16;
      int ar = arow0 + r;
      if (ar > armax) ar = armax;
      As[tx][r] = A[ar * 512 + k0 + tx];
      Bs[tx][r] = W1[(h0 + r) * 1024 + koff + k0 + tx];
    }
    __syncthreads();
#pragma unroll
    for (int kk = 0; kk < 16; ++kk) {
      f32x4 a = *(const f32x4*)&As[kk][ty * 4];
      f32x4 b = *(const f32x4*)&Bs[kk][tx * 4];
#pragma unroll
      for (int i = 0; i < 4; ++i)
#pragma unroll
        for (int j = 0; j < 4; ++j) acc[i][j] += a[i] * b[j];
    }
    __syncthreads();
  }
#pragma unroll
  for (int i = 0; i < 4; ++i) {
    int m = m0 + ty * 4 + i;
    if (m < 2000) {
#pragma unroll
      for (int j = 0; j < 4; ++j) {
        int h = h0 + tx * 4 + j;
        float val = acc[i][j];
        if (m >= 1600) val += b1[h];
        EPPB[m * HDIM + h] = val;
      }
    }
  }
}

// ---- K1b: hidden = tanh(ep + pb) -> bf16 Hb[80128][640], linear, once ----
__global__ __launch_bounds__(256) void k_hidden(const float* __restrict__ EPPB,
                                                unsigned short* __restrict__ Hb) {
  const int tid = threadIdx.x;
  const int wave = tid >> 6, lane = tid & 63;
  const int r = lane >> 3, c = lane & 7;
  const int m = blockIdx.x * 32 + wave * 8 + r;
  const int ms = (m < 80000) ? m : 79999;  // pad rows clone last row
  const int n = ms / 10000;
  const int rr = ms - n * 10000;
  const int t = rr / 50;
  const int u = rr - t * 50;
  const float* ep = EPPB + (t * 8 + n) * HDIM + c * 8;
  const float* pb = EPPB + (1600 + u * 8 + n) * HDIM + c * 8;
  unsigned short* hrow = Hb + (size_t)m * HDIM + c * 8;
#pragma unroll
  for (int it = 0; it < 10; ++it) {
    const int k = it * 64;
    f32x4 e0 = *(const f32x4*)(ep + k);
    f32x4 e1 = *(const f32x4*)(ep + k + 4);
    f32x4 p0 = *(const f32x4*)(pb + k);
    f32x4 p1 = *(const f32x4*)(pb + k + 4);
    s16x8 h;
#pragma unroll
    for (int i = 0; i < 4; ++i) {
      h[i] = (short)f2bf(tanh_fast(e0[i] + p0[i]));
      h[i + 4] = (short)f2bf(tanh_fast(e1[i] + p1[i]));
    }
    *(s16x8*)(hrow + k) = h;
  }
}

// ---- K2: 256m x 256v, BK=64, 4-phase interleaved pipeline ----
// LDS: A [dbuf][half][128][128B] at 0..65535; B same at 65536..131071.
// half = parity of 16-row group (mi&1 / ni&1). Swizzle: byte ^ ((img_row&7)<<4),
// applied on global SOURCE (stage) and on ds_read address; img_row&7 == lr&7.

#define VM4 asm volatile("s_waitcnt vmcnt(4)" ::: "memory")
#define VM0 asm volatile("s_waitcnt vmcnt(0)" ::: "memory")
#define LGKM0 asm volatile("s_waitcnt lgkmcnt(0)" ::: "memory")
#define SBAR __builtin_amdgcn_s_barrier()
#define SCHB __builtin_amdgcn_sched_barrier(0)

#define RD_A(MP)                                                          \
  _Pragma("unroll") for (int g = 0; g < 4; ++g)                           \
  _Pragma("unroll") for (int kk = 0; kk < 2; ++kk)                        \
    afr[g][kk] = *(const s16x8*)(lds + cb + (MP)*16384 + g*2048 + aB + kb[kk])

#define RD_B(VP)                                                          \
  _Pragma("unroll") for (int vg = 0; vg < 2; ++vg)                        \
  _Pragma("unroll") for (int kk = 0; kk < 2; ++kk)                        \
    bfr[vg][kk] = *(const s16x8*)(lds + 65536 + cb + (VP)*16384 + vg*2048 + bB + kb[kk])

#define STG_A(h)                                                          \
  do {                                                                    \
    gload_lds16(aSrc + off[h][0] + tB, lds + nb + (h)*16384 + dst0);      \
    gload_lds16(aSrc + off[h][1] + tB, lds + nb + (h)*16384 + dst1);      \
  } while (0)

#define STG_B(h)                                                          \
  do {                                                                    \
    gload_lds16(bSrc + off[h][0] + tB, lds + nb + 65536 + (h)*16384 + dst0); \
    gload_lds16(bSrc + off[h][1] + tB, lds + nb + 65536 + (h)*16384 + dst1); \
  } while (0)

#define MM(MP, VP)                                                        \
  __builtin_amdgcn_s_setprio(1);                                          \
  _Pragma("unroll") for (int g = 0; g < 4; ++g)                           \
  _Pragma("unroll") for (int vg = 0; vg < 2; ++vg)                        \
  _Pragma("unroll") for (int kk = 0; kk < 2; ++kk)                        \
    acc[2*g + MP][2*vg + VP] = __builtin_amdgcn_mfma_f32_16x16x32_bf16(   \
        bfr[vg][kk], afr[g][kk], acc[2*g + MP][2*vg + VP], 0, 0, 0);      \
  __builtin_amdgcn_s_setprio(0)

__global__ __launch_bounds__(512, 1) void k_joint(const unsigned short* __restrict__ Hb,
                                                  const unsigned short* __restrict__ W2b,
                                                  const float* __restrict__ b2,
                                                  float* __restrict__ out) {
  extern __shared__ char lds[];  // 131072

  // bijective XCD-chunked swizzle over 1252 WGs (1252 = 8*156 + 4); vtile-minor
  const int bid = blockIdx.x;
  const int xcd = bid & 7, seq = bid >> 3;
  const int swz = (xcd < 4 ? xcd * 157 : 628 + (xcd - 4) * 156) + seq;
  const int mtile = swz >> 2;
  const int vtile = swz & 3;
  const int m0 = mtile * 256;  // Hb padded to 80128 rows
  const int v0 = vtile * 256;

  const int tid = threadIdx.x;
  const int wid = tid >> 6;
  const int lane = tid & 63;
  const int wm = wid >> 2;   // 2 m-wave-groups
  const int wv = wid & 3;    // 4 v-wave-groups
  const int lr = lane & 15;
  const int kq = lane >> 4;

  // staging source offsets: chunk c = s*512+tid: img_row=c>>3, kc=c&7
  // half h -> tile row r = ((img_row>>4)*2 + h)*16 + (img_row&15)
  const char* const aSrc = (const char*)Hb + (size_t)m0 * 1280;
  const char* const bSrc = (const char*)W2b + (size_t)v0 * 1280;
  int off[2][2];
#pragma unroll
  for (int s = 0; s < 2; ++s) {
    int c = s * 512 + tid;
    int ir = c >> 3, kc = c & 7;
    int sz = (kc * 16) ^ ((ir & 7) << 4);
#pragma unroll
    for (int h = 0; h < 2; ++h) {
      int r = ((ir >> 4) * 2 + h) * 16 + (ir & 15);
      off[h][s] = r * 1280 + sz;
    }
  }
  const int dst0 = tid * 16;
  const int dst1 = tid * 16 + 8192;

  // ds_read bases: img_row = (wm*4 + g)*16 + lr  (A);  (wv*2 + vg)*16 + lr  (B)
  const int aB = wm * 8192 + lr * 128;
  const int bB = wv * 4096 + lr * 128;
  const int swl = (lr & 7) << 4;
  int kb[2];
  kb[0] = (kq * 16) ^ swl;
  kb[1] = (64 + kq * 16) ^ swl;

  f32x4 acc[8][4];
  const f32x4 zero = {0.0f, 0.0f, 0.0f, 0.0f};
#pragma unroll
  for (int mi = 0; mi < 8; ++mi)
#pragma unroll
    for (int ni = 0; ni < 4; ++ni) acc[mi][ni] = zero;

  s16x8 afr[4][2], bfr[2][2];

  // prologue: stage ktile0 (all 4 halves of A and B) into buf0, then RETIRE+PUBLISH
  // before the first ds_read (R11's NaN: c0@t0 read LDS before these loads landed).
  {
    const int nb = 0;
    const int tB = 0;
    STG_A(0); STG_B(0); STG_A(1); STG_B(1);
  }
  VM0;
  SCHB;
  SBAR;

#pragma unroll 1
  for (int t = 0; t < 10; ++t) {
    const int cb = (t & 1) << 15;
    const int nb = ((t + 1) & 1) << 15;
    const int tB = (t + 1) * 128;
    const bool pf = (t < 9);

    // phase c0: quadrant (mEven, vEven); stage A-E,B-E of t+1; wait covers B-O,A-O of t
    RD_A(0); RD_B(0);
    if (pf) { STG_A(0); STG_B(0); VM4; } else { VM0; }
    SCHB; SBAR; LGKM0; SCHB;
    MM(0, 0);

    // phase c1: (mEven, vOdd); stage B-O of t+1
    RD_B(1);
    if (pf) STG_B(1);
    SCHB; SBAR; LGKM0; SCHB;
    MM(0, 1);

    // phase c2: (mOdd, vOdd); stage A-O of t+1
    RD_A(1);
    if (pf) STG_A(1);
    SCHB; SBAR; LGKM0; SCHB;
    MM(1, 1);

    // phase c3: (mOdd, vEven); wait covers A-E,B-E of t+1 (first used next c0)
    RD_B(0);
    if (pf) VM4;
    SCHB; SBAR; LGKM0; SCHB;
    MM(1, 0);
  }

  // epilogue: lane holds 4 consecutive v per acc reg -> float4 stores
#pragma unroll
  for (int ni = 0; ni < 4; ++ni) {
    int vq = v0 + wv * 64 + ni * 16 + kq * 4;
    if (vq < VOCAB) {
      f32x4 bv = *(const f32x4*)(b2 + vq);
#pragma unroll
      for (int mi = 0; mi < 8; ++mi) {
        int m = m0 + wm * 128 + mi * 16 + lr;
        if (m < 80000) {
          f32x4 r = acc[mi][ni] + bv;
          *(f32x4*)(out + (size_t)m * VOCAB + vq) = r;
        }
      }
    }
  }
}

// ---- Fallback: round-7 fused kernel (proven) if workspace too small ----
__global__ __launch_bounds__(256, 2) void k_joint_fused(const float* __restrict__ EPPB,
                                                        const unsigned short* __restrict__ W2b,
                                                        const float* __restrict__ b2,
                                                        float* __restrict__ out) {
  __shared__ char Asm[16384];
  __shared__ char Bsm[32768];

  const int bid = blockIdx.x;
  const int xcd = bid & 7, seq = bid >> 3;
  const int swz = (xcd < 4 ? xcd * 313 : 1252 + (xcd - 4) * 312) + seq;
  const int mtile = swz >> 2;
  const int vtile = swz & 3;
  const int m0 = mtile * 128;
  const int v0 = vtile * 256;

  const int tid = threadIdx.x;

  int epoff[4], pboff[4], aoff[4];
#pragma unroll
  for (int s = 0; s < 4; ++s) {
    int c = s * 256 + tid;
    int row = c >> 3, kc = c & 7;
    int m = m0 + row;
    int n = m / 10000;
    int rr = m - n * 10000;
    int t = rr / 50;
    int u = rr - t * 50;
    epoff[s] = (t * 8 + n) * HDIM + kc * 8;
    pboff[s] = (1600 + u * 8 + n) * HDIM + kc * 8;
    aoff[s] = row * 128 + ((kc * 16) ^ ((row & 7) << 4));
  }

  const char* const w2bytes = (const char*)W2b;
  int bgoff[8];
#pragma unroll
  for (int s = 0; s < 8; ++s) {
    int c = s * 256 + tid;
    int row = c >> 3, kc = c & 7;
    bgoff[s] = (v0 + row) * 1280 + ((kc * 16) ^ ((row & 7) << 4));
  }
  const int bldsbase = (tid >> 6) * 1024;

  const int wid = tid >> 6;
  const int lane = tid & 63;
  const int mrow = (wid >> 1) * 64;
  const int vrow = (wid & 1) * 128;
  const int lr = lane & 15;
  const int kq = lane >> 4;
  const int sw = (lr & 7) << 4;

  f32x4 acc[4][8];
  const f32x4 zero = {0.0f, 0.0f, 0.0f, 0.0f};
#pragma unroll
  for (int mi = 0; mi < 4; ++mi)
#pragma unroll
    for (int ni = 0; ni < 8; ++ni) acc[mi][ni] = zero;

#pragma unroll 1
  for (int ks = 0; ks < 10; ++ks) {
    s16x8 aq[4];
#pragma unroll
    for (int s = 0; s < 4; ++s) {
      const float* ep = EPPB + epoff[s] + ks * 64;
      const float* pb = EPPB + pboff[s] + ks * 64;
      f32x4 e0 = *(const f32x4*)ep;
      f32x4 e1 = *(const f32x4*)(ep + 4);
      f32x4 p0 = *(const f32x4*)pb;
      f32x4 p1 = *(const f32x4*)(pb + 4);
#pragma unroll
      for (int i = 0; i < 4; ++i) {
        aq[s][i] = (short)f2bf(tanh_fast(e0[i] + p0[i]));
        aq[s][i + 4] = (short)f2bf(tanh_fast(e1[i] + p1[i]));
      }
    }
    __syncthreads();
#pragma unroll
    for (int s = 0; s < 8; ++s)
      gload_lds16(w2bytes + bgoff[s] + ks * 128, Bsm + s * 4096 + bldsbase);
#pragma unroll
    for (int s = 0; s < 4; ++s) *(s16x8*)(Asm + aoff[s]) = aq[s];
    __syncthreads();

#pragma unroll
    for (int kk = 0; kk < 2; ++kk) {
      const int kt = (kk * 64 + kq * 16) ^ sw;
      s16x8 afr[4], bfr[8];
#pragma unroll
      for (int mi = 0; mi < 4; ++mi)
        afr[mi] = *(const s16x8*)(Asm + (mrow + mi * 16 + lr) * 128 + kt);
#pragma unroll
      for (int ni = 0; ni < 8; ++ni)
        bfr[ni] = *(const s16x8*)(Bsm + (vrow + ni * 16 + lr) * 128 + kt);
      __builtin_amdgcn_s_setprio(1);
#pragma unroll
      for (int mi = 0; mi < 4; ++mi)
#pragma unroll
        for (int ni = 0; ni < 8; ++ni)
          acc[mi][ni] = __builtin_amdgcn_mfma_f32_16x16x32_bf16(bfr[ni], afr[mi], acc[mi][ni], 0, 0, 0);
      __builtin_amdgcn_s_setprio(0);
    }
  }

#pragma unroll
  for (int ni = 0; ni < 8; ++ni) {
    int vq = v0 + vrow + ni * 16 + kq * 4;
    if (vq < VOCAB) {
      f32x4 bv = *(const f32x4*)(b2 + vq);
#pragma unroll
      for (int mi = 0; mi < 4; ++mi) {
        int m = m0 + mrow + mi * 16 + lr;
        f32x4 r = acc[mi][ni] + bv;
        *(f32x4*)(out + (size_t)m * VOCAB + vq) = r;
      }
    }
  }
}

extern "C" void kernel_launch(void* const* d_in, const int* in_sizes, int n_in,
                              void* d_out, int out_size, void* d_ws, size_t ws_size,
                              hipStream_t stream) {
  const float* enc = (const float*)d_in[0];
  const float* pred = (const float*)d_in[1];
  const float* W1 = (const float*)d_in[2];
  const float* b1 = (const float*)d_in[3];
  const float* W2 = (const float*)d_in[4];
  const float* b2 = (const float*)d_in[5];
  float* out = (float*)d_out;

  unsigned short* W2b = (unsigned short*)d_ws;                    // 1,310,720 B
  float* EPPB = (float*)((char*)d_ws + 1310720);                  // 5,120,000 B
  unsigned short* Hb = (unsigned short*)((char*)d_ws + 6430720);  // 80128*1280 B

  k_prep<<<320, 256, 0, stream>>>(W2, W2b);
  k_proj<<<dim3(10, 32), 256, 0, stream>>>(enc, pred, W1, b1, EPPB);

  if (ws_size >= (size_t)108994560) {
    hipFuncSetAttribute((const void*)k_joint, hipFuncAttributeMaxDynamicSharedMemorySize, 131072);
    k_hidden<<<2504, 256, 0, stream>>>(EPPB, Hb);
    k_joint<<<1252, 512, 131072, stream>>>(Hb, W2b, b2, out);
  } else {
    k_joint_fused<<<2500, 256, 0, stream>>>(EPPB, W2b, b2, out);
  }
}

// Round 13
// 275.801 us; speedup vs baseline: 1.0739x; 1.0273x over previous
//
#include <hip/hip_runtime.h>

// JointNet: out[n,t,u,v] = tanh(enc_proj[t,n,:] + pred_proj[u,n,:] + b1) . W2^T + b2
// T=200 U=50 N=8  ENC=PRED=512  H=640  V=1000
// m = ((n*200+t)*50+u) -> flat row-major [80000][1000] GEMM.
// Round-13: R8's proven 2-phase pure-GEMM skeleton resized for 3 WGs/CU (m97's
// occupancy regime): 96m x 256v tile, acc[3][8]=96 regs, 44KB LDS, (256,3).
// Both operands via global_load_lds (pre-swizzled source, linear LDS dest).

typedef __attribute__((ext_vector_type(4))) float f32x4;
typedef __attribute__((ext_vector_type(8))) short s16x8;

#define HDIM 640
#define VOCAB 1000

__device__ __forceinline__ float tanh_fast(float x) {
  float e = __expf(2.0f * x);
  return 1.0f - 2.0f * __builtin_amdgcn_rcpf(e + 1.0f);
}

__device__ __forceinline__ unsigned short f2bf(float f) {
  unsigned int u = __float_as_uint(f);
  return (unsigned short)((u + 0x7FFFu + ((u >> 16) & 1u)) >> 16);  // RNE
}

__device__ __forceinline__ void gload_lds16(const void* g, void* l) {
  __builtin_amdgcn_global_load_lds((const __attribute__((address_space(1))) void*)g,
                                   (__attribute__((address_space(3))) void*)l, 16, 0, 0);
}

// ---- K0: W2 f32 [1000][640] -> bf16 [1024][640], rows 1000..1023 zero ----
__global__ void k_prep(const float* __restrict__ W2, unsigned short* __restrict__ W2b) {
  int i = blockIdx.x * 256 + threadIdx.x;  // 81920 = 1024*640/8
  int v = i / 80;
  int kc = (i - v * 80) * 8;
  s16x8 o = {0, 0, 0, 0, 0, 0, 0, 0};
  if (v < VOCAB) {
    const float* src = W2 + v * HDIM + kc;
    f32x4 a = *(const f32x4*)src;
    f32x4 b = *(const f32x4*)(src + 4);
#pragma unroll
    for (int j = 0; j < 4; ++j) {
      o[j] = (short)f2bf(a[j]);
      o[j + 4] = (short)f2bf(b[j]);
    }
  }
  *(s16x8*)(W2b + (size_t)v * HDIM + kc) = o;
}

// ---- K1: projections, f32 tiled GEMM ----
__global__ __launch_bounds__(256) void k_proj(const float* __restrict__ enc,
                                              const float* __restrict__ pred,
                                              const float* __restrict__ W1,
                                              const float* __restrict__ b1,
                                              float* __restrict__ EPPB) {
  __shared__ float As[16][68];
  __shared__ float Bs[16][68];
  const int tid = threadIdx.x;
  const int tx = tid & 15, ty = tid >> 4;
  const int h0 = blockIdx.x * 64;
  const int m0 = blockIdx.y * 64;
  const bool isPred = (m0 >= 1600);
  const float* A = isPred ? pred : enc;
  const int arow0 = isPred ? (m0 - 1600) : m0;
  const int armax = isPred ? 399 : 1599;
  const int koff = isPred ? 512 : 0;
  float acc[4][4] = {};
  for (int k0 = 0; k0 < 512; k0 += 16) {
#pragma unroll
    for (int q = 0; q < 4; ++q) {
      int r = ty + q * 16;
      int ar = arow0 + r;
      if (ar > armax) ar = armax;
      As[tx][r] = A[ar * 512 + k0 + tx];
      Bs[tx][r] = W1[(h0 + r) * 1024 + koff + k0 + tx];
    }
    __syncthreads();
#pragma unroll
    for (int kk = 0; kk < 16; ++kk) {
      f32x4 a = *(const f32x4*)&As[kk][ty * 4];
      f32x4 b = *(const f32x4*)&Bs[kk][tx * 4];
#pragma unroll
      for (int i = 0; i < 4; ++i)
#pragma unroll
        for (int j = 0; j < 4; ++j) acc[i][j] += a[i] * b[j];
    }
    __syncthreads();
  }
#pragma unroll
  for (int i = 0; i < 4; ++i) {
    int m = m0 + ty * 4 + i;
    if (m < 2000) {
#pragma unroll
      for (int j = 0; j < 4; ++j) {
        int h = h0 + tx * 4 + j;
        float val = acc[i][j];
        if (m >= 1600) val += b1[h];
        EPPB[m * HDIM + h] = val;
      }
    }
  }
}

// ---- K1b: hidden = tanh(ep + pb) -> bf16 Hb[80064][640], linear, once ----
__global__ __launch_bounds__(256) void k_hidden(const float* __restrict__ EPPB,
                                                unsigned short* __restrict__ Hb) {
  const int tid = threadIdx.x;
  const int wave = tid >> 6, lane = tid & 63;
  const int r = lane >> 3, c = lane & 7;
  const int m = blockIdx.x * 32 + wave * 8 + r;
  const int ms = (m < 80000) ? m : 79999;  // pad rows clone last row
  const int n = ms / 10000;
  const int rr = ms - n * 10000;
  const int t = rr / 50;
  const int u = rr - t * 50;
  const float* ep = EPPB + (t * 8 + n) * HDIM + c * 8;
  const float* pb = EPPB + (1600 + u * 8 + n) * HDIM + c * 8;
  unsigned short* hrow = Hb + (size_t)m * HDIM + c * 8;
#pragma unroll
  for (int it = 0; it < 10; ++it) {
    const int k = it * 64;
    f32x4 e0 = *(const f32x4*)(ep + k);
    f32x4 e1 = *(const f32x4*)(ep + k + 4);
    f32x4 p0 = *(const f32x4*)(pb + k);
    f32x4 p1 = *(const f32x4*)(pb + k + 4);
    s16x8 h;
#pragma unroll
    for (int i = 0; i < 4; ++i) {
      h[i] = (short)f2bf(tanh_fast(e0[i] + p0[i]));
      h[i + 4] = (short)f2bf(tanh_fast(e1[i] + p1[i]));
    }
    *(s16x8*)(hrow + k) = h;
  }
}

// ---- K2: pure GEMM 96m x 256v, BK=64, 2-phase single-buffer, 3 WGs/CU ----
__global__ __launch_bounds__(256, 3) void k_joint(const unsigned short* __restrict__ Hb,
                                                  const unsigned short* __restrict__ W2b,
                                                  const float* __restrict__ b2,
                                                  float* __restrict__ out) {
  __shared__ char Asm[12288];  // A: 96 rows x 128 B, XOR-swizzled image
  __shared__ char Bsm[32768];  // B: 256 rows x 128 B, XOR-swizzled image

  // XCD swizzle over 3336 WGs (3336 = 8*417, clean); vtile-minor for A L2 reuse
  const int bid = blockIdx.x;
  const int xcd = bid & 7, seq = bid >> 3;
  const int swz = xcd * 417 + seq;
  const int mtile = swz >> 2;
  const int vtile = swz & 3;
  const int m0 = mtile * 96;   // 834 mtiles; Hb padded to 80064 rows
  const int v0 = vtile * 256;

  const int tid = threadIdx.x;

  // staging bases: chunk c = s*256+tid -> row = s*32 + (tid>>3), kc = tid&7.
  // +s*40960 keeps swizzle invariant (32 rows = 0 mod 8).
  const char* const hbytes = (const char*)Hb;
  const char* const w2bytes = (const char*)W2b;
  const int srow = tid >> 3, skc = tid & 7;
  const int ssw = (skc * 16) ^ ((srow & 7) << 4);
  const int agoff0 = (m0 + srow) * 1280 + ssw;
  const int bgoff0 = (v0 + srow) * 1280 + ssw;
  const int ldst = tid * 16;

  const int wid = tid >> 6;
  const int lane = tid & 63;
  const int mrow = (wid >> 1) * 48;  // 2 m-waves x 2 v-waves; wave = 48m x 128v
  const int vrow = (wid & 1) * 128;
  const int lr = lane & 15;
  const int kq = lane >> 4;
  const int sw = (lr & 7) << 4;

  f32x4 acc[3][8];
  const f32x4 zero = {0.0f, 0.0f, 0.0f, 0.0f};
#pragma unroll
  for (int mi = 0; mi < 3; ++mi)
#pragma unroll
    for (int ni = 0; ni < 8; ++ni) acc[mi][ni] = zero;

#pragma unroll 1
  for (int ks = 0; ks < 10; ++ks) {
    __syncthreads();  // prior MFMA phase done reading LDS (WAR)
#pragma unroll
    for (int s = 0; s < 3; ++s)
      gload_lds16(hbytes + agoff0 + s * 40960 + ks * 128, Asm + s * 4096 + ldst);
#pragma unroll
    for (int s = 0; s < 8; ++s)
      gload_lds16(w2bytes + bgoff0 + s * 40960 + ks * 128, Bsm + s * 4096 + ldst);
    __syncthreads();  // staged data visible (vmcnt drained by barrier semantics)

#pragma unroll
    for (int kk = 0; kk < 2; ++kk) {
      const int kt = (kk * 64 + kq * 16) ^ sw;
      s16x8 afr[3];
#pragma unroll
      for (int mi = 0; mi < 3; ++mi)
        afr[mi] = *(const s16x8*)(Asm + (mrow + mi * 16 + lr) * 128 + kt);
#pragma unroll
      for (int ni = 0; ni < 8; ++ni) {
        // read one B frag, consume immediately (caps live VGPRs at (256,3) budget)
        s16x8 bfr = *(const s16x8*)(Bsm + (vrow + ni * 16 + lr) * 128 + kt);
        __builtin_amdgcn_s_setprio(1);
#pragma unroll
        for (int mi = 0; mi < 3; ++mi)
          // swapped operands: D row = v (4 consecutive per lane), col = m
          acc[mi][ni] = __builtin_amdgcn_mfma_f32_16x16x32_bf16(bfr, afr[mi], acc[mi][ni], 0, 0, 0);
        __builtin_amdgcn_s_setprio(0);
      }
    }
  }

  // epilogue: lane holds 4 consecutive v per acc reg -> float4 stores
#pragma unroll
  for (int ni = 0; ni < 8; ++ni) {
    int vq = v0 + vrow + ni * 16 + kq * 4;
    if (vq < VOCAB) {
      f32x4 bv = *(const f32x4*)(b2 + vq);
#pragma unroll
      for (int mi = 0; mi < 3; ++mi) {
        int m = m0 + mrow + mi * 16 + lr;
        if (m < 80000) {
          f32x4 r = acc[mi][ni] + bv;
          *(f32x4*)(out + (size_t)m * VOCAB + vq) = r;
        }
      }
    }
  }
}

// ---- Fallback: round-7 fused kernel (proven) if workspace too small ----
__global__ __launch_bounds__(256, 2) void k_joint_fused(const float* __restrict__ EPPB,
                                                        const unsigned short* __restrict__ W2b,
                                                        const float* __restrict__ b2,
                                                        float* __restrict__ out) {
  __shared__ char Asm[16384];
  __shared__ char Bsm[32768];

  const int bid = blockIdx.x;
  const int xcd = bid & 7, seq = bid >> 3;
  const int swz = (xcd < 4 ? xcd * 313 : 1252 + (xcd - 4) * 312) + seq;
  const int mtile = swz >> 2;
  const int vtile = swz & 3;
  const int m0 = mtile * 128;
  const int v0 = vtile * 256;

  const int tid = threadIdx.x;

  int epoff[4], pboff[4], aoff[4];
#pragma unroll
  for (int s = 0; s < 4; ++s) {
    int c = s * 256 + tid;
    int row = c >> 3, kc = c & 7;
    int m = m0 + row;
    int n = m / 10000;
    int rr = m - n * 10000;
    int t = rr / 50;
    int u = rr - t * 50;
    epoff[s] = (t * 8 + n) * HDIM + kc * 8;
    pboff[s] = (1600 + u * 8 + n) * HDIM + kc * 8;
    aoff[s] = row * 128 + ((kc * 16) ^ ((row & 7) << 4));
  }

  const char* const w2bytes = (const char*)W2b;
  int bgoff[8];
#pragma unroll
  for (int s = 0; s < 8; ++s) {
    int c = s * 256 + tid;
    int row = c >> 3, kc = c & 7;
    bgoff[s] = (v0 + row) * 1280 + ((kc * 16) ^ ((row & 7) << 4));
  }
  const int bldsbase = (tid >> 6) * 1024;

  const int wid = tid >> 6;
  const int lane = tid & 63;
  const int mrow = (wid >> 1) * 64;
  const int vrow = (wid & 1) * 128;
  const int lr = lane & 15;
  const int kq = lane >> 4;
  const int sw = (lr & 7) << 4;

  f32x4 acc[4][8];
  const f32x4 zero = {0.0f, 0.0f, 0.0f, 0.0f};
#pragma unroll
  for (int mi = 0; mi < 4; ++mi)
#pragma unroll
    for (int ni = 0; ni < 8; ++ni) acc[mi][ni] = zero;

#pragma unroll 1
  for (int ks = 0; ks < 10; ++ks) {
    s16x8 aq[4];
#pragma unroll
    for (int s = 0; s < 4; ++s) {
      const float* ep = EPPB + epoff[s] + ks * 64;
      const float* pb = EPPB + pboff[s] + ks * 64;
      f32x4 e0 = *(const f32x4*)ep;
      f32x4 e1 = *(const f32x4*)(ep + 4);
      f32x4 p0 = *(const f32x4*)pb;
      f32x4 p1 = *(const f32x4*)(pb + 4);
#pragma unroll
      for (int i = 0; i < 4; ++i) {
        aq[s][i] = (short)f2bf(tanh_fast(e0[i] + p0[i]));
        aq[s][i + 4] = (short)f2bf(tanh_fast(e1[i] + p1[i]));
      }
    }
    __syncthreads();
#pragma unroll
    for (int s = 0; s < 8; ++s)
      gload_lds16(w2bytes + bgoff[s] + ks * 128, Bsm + s * 4096 + bldsbase);
#pragma unroll
    for (int s = 0; s < 4; ++s) *(s16x8*)(Asm + aoff[s]) = aq[s];
    __syncthreads();

#pragma unroll
    for (int kk = 0; kk < 2; ++kk) {
      const int kt = (kk * 64 + kq * 16) ^ sw;
      s16x8 afr[4], bfr[8];
#pragma unroll
      for (int mi = 0; mi < 4; ++mi)
        afr[mi] = *(const s16x8*)(Asm + (mrow + mi * 16 + lr) * 128 + kt);
#pragma unroll
      for (int ni = 0; ni < 8; ++ni)
        bfr[ni] = *(const s16x8*)(Bsm + (vrow + ni * 16 + lr) * 128 + kt);
      __builtin_amdgcn_s_setprio(1);
#pragma unroll
      for (int mi = 0; mi < 4; ++mi)
#pragma unroll
        for (int ni = 0; ni < 8; ++ni)
          acc[mi][ni] = __builtin_amdgcn_mfma_f32_16x16x32_bf16(bfr[ni], afr[mi], acc[mi][ni], 0, 0, 0);
      __builtin_amdgcn_s_setprio(0);
    }
  }

#pragma unroll
  for (int ni = 0; ni < 8; ++ni) {
    int vq = v0 + vrow + ni * 16 + kq * 4;
    if (vq < VOCAB) {
      f32x4 bv = *(const f32x4*)(b2 + vq);
#pragma unroll
      for (int mi = 0; mi < 4; ++mi) {
        int m = m0 + mrow + mi * 16 + lr;
        f32x4 r = acc[mi][ni] + bv;
        *(f32x4*)(out + (size_t)m * VOCAB + vq) = r;
      }
    }
  }
}

extern "C" void kernel_launch(void* const* d_in, const int* in_sizes, int n_in,
                              void* d_out, int out_size, void* d_ws, size_t ws_size,
                              hipStream_t stream) {
  const float* enc = (const float*)d_in[0];
  const float* pred = (const float*)d_in[1];
  const float* W1 = (const float*)d_in[2];
  const float* b1 = (const float*)d_in[3];
  const float* W2 = (const float*)d_in[4];
  const float* b2 = (const float*)d_in[5];
  float* out = (float*)d_out;

  unsigned short* W2b = (unsigned short*)d_ws;                    // 1,310,720 B
  float* EPPB = (float*)((char*)d_ws + 1310720);                  // 5,120,000 B
  unsigned short* Hb = (unsigned short*)((char*)d_ws + 6430720);  // 80064*1280 B

  k_prep<<<320, 256, 0, stream>>>(W2, W2b);
  k_proj<<<dim3(10, 32), 256, 0, stream>>>(enc, pred, W1, b1, EPPB);

  if (ws_size >= (size_t)108912640) {
    k_hidden<<<2502, 256, 0, stream>>>(EPPB, Hb);   // 2502*32 = 80064 rows
    k_joint<<<3336, 256, 0, stream>>>(Hb, W2b, b2, out);
  } else {
    k_joint_fused<<<2500, 256, 0, stream>>>(EPPB, W2b, b2, out);
  }
}